// Round 2
// baseline (95.523 us; speedup 1.0000x reference)
//
#include <hip/hip_runtime.h>
#include <hip/hip_bf16.h>

// Problem: B=2, N=1024, D=30, H=64, O=30  (all fp32)
//   zi = z @ W_r[:D], zj = z @ W_r[D:]
//   r_sum[b,i,h] = sum_j relu(zi[b,i,h] + zj[b,j,h] + b_r[h])
//   out[b,i,o]   = relu(sum_h r_sum[b,i,h]*W_a[h,o] + b_a[o])

#define BB 2
#define NN 1024
#define DD 30
#define HH 64
#define OO 30
#define JT 128      // j-tile rows staged in LDS (128*64*4B = 32 KB)
#define ITILE 8     // i rows per block (4 waves x 2 packed rows)

typedef float v2f __attribute__((ext_vector_type(2)));

// Kernel A: compute zi[b,n,h] and zjb[b,n,h] = zj + b_r  (b_r folded here)
__global__ __launch_bounds__(256) void proj_kernel(
    const float* __restrict__ z,    // [B*N, D]
    const float* __restrict__ Wr,   // [2D, H]
    const float* __restrict__ br,   // [H]
    float* __restrict__ zi_out,     // [B*N, H]
    float* __restrict__ zjb_out)    // [B*N, H]
{
    const int h = threadIdx.x;                      // 0..63
    const int r = blockIdx.x * 4 + threadIdx.y;     // row in [0, B*N)
    const float* zrow = z + (size_t)r * DD;
    float wi = 0.f, wj = 0.f;
#pragma unroll
    for (int d = 0; d < DD; ++d) {
        const float zv = zrow[d];                   // wave-uniform (scalar)
        wi += zv * Wr[d * HH + h];                  // coalesced across lanes
        wj += zv * Wr[(DD + d) * HH + h];
    }
    zi_out [(size_t)r * HH + h] = wi;
    zjb_out[(size_t)r * HH + h] = wj + br[h];
}

// Kernel B: pairwise relu-sum over j, fused with the H->O epilogue GEMM.
// Grid: (N/ITILE, B). Block: (64, 4). Lane = h. Wave w owns i-rows
// (i0+2w, i0+2w+1), packed into the two halves of a float2 lane so the
// inner body is 3 packed VALU (v_pk_add / v_pk_max / v_pk_add) per j.
__global__ __launch_bounds__(256) void pairsum_kernel(
    const float* __restrict__ zi,    // [B*N, H]
    const float* __restrict__ zjb,   // [B*N, H]
    const float* __restrict__ Wa,    // [H, O]
    const float* __restrict__ ba,    // [O]
    float* __restrict__ out)         // [B*N, O]
{
    __shared__ float sj[JT * HH];        // 32 KB j-tile
    __shared__ float racc[ITILE][HH];    // 2 KB r_sum rows

    const int h  = threadIdx.x;          // 0..63
    const int w  = threadIdx.y;          // 0..3
    const int t  = w * 64 + h;           // 0..255
    const int b  = blockIdx.y;
    const int i0 = blockIdx.x * ITILE;

    const float* zbase = zi + ((size_t)b * NN + i0) * HH;
    v2f zv;
    zv.x = zbase[(w * 2 + 0) * HH + h];
    zv.y = zbase[(w * 2 + 1) * HH + h];

    v2f accA = {0.f, 0.f};               // even-j chain
    v2f accB = {0.f, 0.f};               // odd-j chain
    const v2f zero = {0.f, 0.f};

    const float* zjb_b = zjb + (size_t)b * NN * HH;
    const float4* src = (const float4*)zjb_b;     // 2048 float4 per tile

    // prefetch tile 0 into registers
    float4 reg[8];
#pragma unroll
    for (int k = 0; k < 8; ++k) reg[k] = src[t + k * 256];

    for (int tile = 0; tile < NN / JT; ++tile) {
        __syncthreads();                 // previous tile's consumers done
        float4* dst = (float4*)sj;
#pragma unroll
        for (int k = 0; k < 8; ++k) dst[t + k * 256] = reg[k];
        __syncthreads();

        if (tile < NN / JT - 1) {        // prefetch next tile (overlaps compute)
            const float4* s2 = src + (size_t)(tile + 1) * (JT * HH / 4);
#pragma unroll
            for (int k = 0; k < 8; ++k) reg[k] = s2[t + k * 256];
        }

#pragma unroll 16
        for (int j = 0; j < JT; j += 2) {
            const float s0 = sj[(j + 0) * HH + h];   // 2-way bank alias: free
            const float s1 = sj[(j + 1) * HH + h];
            v2f t0 = zv + s0;                        // scalar broadcasts
            v2f t1 = zv + s1;
            t0 = __builtin_elementwise_max(t0, zero);
            t1 = __builtin_elementwise_max(t1, zero);
            accA += t0;
            accB += t1;
        }
    }

    racc[w * 2 + 0][h] = accA.x + accB.x;
    racc[w * 2 + 1][h] = accA.y + accB.y;
    __syncthreads();

    // Epilogue: 8 rows x 30 outputs = 240 dots of length 64
    const int i = t >> 5;        // 0..7
    const int o = t & 31;        // 0..31
    if (o < OO) {
        float s = ba[o];
#pragma unroll
        for (int hh = 0; hh < HH; ++hh)
            s += racc[i][hh] * Wa[hh * OO + o];   // racc broadcast, Wa cached
        out[((size_t)b * NN + i0 + i) * OO + o] = fmaxf(s, 0.f);
    }
}

extern "C" void kernel_launch(void* const* d_in, const int* in_sizes, int n_in,
                              void* d_out, int out_size, void* d_ws, size_t ws_size,
                              hipStream_t stream) {
    const float* z_t = (const float*)d_in[0];   // [B,N,D]
    const float* W_r = (const float*)d_in[1];   // [2D,H]
    const float* b_r = (const float*)d_in[2];   // [H]
    const float* W_a = (const float*)d_in[3];   // [H,O]
    const float* b_a = (const float*)d_in[4];   // [O]
    float* out = (float*)d_out;                 // [B,N,O]

    float* zi  = (float*)d_ws;                  // B*N*H floats
    float* zjb = zi + (size_t)BB * NN * HH;     // B*N*H floats (1 MB total)

    proj_kernel<<<dim3((BB * NN) / 4), dim3(64, 4), 0, stream>>>(
        z_t, W_r, b_r, zi, zjb);
    pairsum_kernel<<<dim3(NN / ITILE, BB), dim3(64, 4), 0, stream>>>(
        zi, zjb, W_a, b_a, out);
}

// Round 3
// 85.459 us; speedup vs baseline: 1.1178x; 1.1178x over previous
//
#include <hip/hip_runtime.h>
#include <hip/hip_bf16.h>

// Problem: B=2, N=1024, D=30, H=64, O=30  (all fp32)
//   zi = z @ W_r[:D], zj = z @ W_r[D:]
//   r_sum[b,i,h] = sum_j relu(zi[b,i,h] + zj[b,j,h] + b_r[h])
//   out[b,i,o]   = relu(sum_h r_sum[b,i,h]*W_a[h,o] + b_a[o])
//
// R2 post-mortem: dur_us is dominated by ~81 us of harness d_ws poison
// fills (2 x 268 MB @ ~6.6 TB/s, visible as fillBufferAligned in rocprof).
// Kernel portion is ~5 us. R2's packed/prefetch restructure regressed the
// kernel portion ~3x; this reverts to the measured-best R1 structure.

#define BB 2
#define NN 1024
#define DD 30
#define HH 64
#define OO 30
#define JT 128      // j-tile rows staged in LDS (128*64*4B = 32 KB)
#define ITILE 8     // i rows per block (4 waves x 2 accumulators)

// Kernel A: compute zi[b,n,h] and zjb[b,n,h] = zj + b_r  (b_r folded here)
__global__ __launch_bounds__(256) void proj_kernel(
    const float* __restrict__ z,    // [B*N, D]
    const float* __restrict__ Wr,   // [2D, H]
    const float* __restrict__ br,   // [H]
    float* __restrict__ zi_out,     // [B*N, H]
    float* __restrict__ zjb_out)    // [B*N, H]
{
    const int h = threadIdx.x;                      // 0..63
    const int r = blockIdx.x * 4 + threadIdx.y;     // row in [0, B*N)
    const float* zrow = z + (size_t)r * DD;
    float wi = 0.f, wj = 0.f;
#pragma unroll
    for (int d = 0; d < DD; ++d) {
        const float zv = zrow[d];                   // wave-uniform (scalar)
        wi += zv * Wr[d * HH + h];                  // coalesced across lanes
        wj += zv * Wr[(DD + d) * HH + h];
    }
    zi_out [(size_t)r * HH + h] = wi;
    zjb_out[(size_t)r * HH + h] = wj + br[h];
}

// Kernel B: pairwise relu-sum over j, fused with the H->O epilogue GEMM.
// Grid: (N/ITILE, B). Block: (64, 4). Lane = h. Wave w owns i = i0+2w, i0+2w+1.
__global__ __launch_bounds__(256) void pairsum_kernel(
    const float* __restrict__ zi,    // [B*N, H]
    const float* __restrict__ zjb,   // [B*N, H]
    const float* __restrict__ Wa,    // [H, O]
    const float* __restrict__ ba,    // [O]
    float* __restrict__ out)         // [B*N, O]
{
    __shared__ float sj[JT * HH];        // 32 KB j-tile
    __shared__ float racc[ITILE][HH];    // 2 KB r_sum rows

    const int h  = threadIdx.x;          // 0..63
    const int w  = threadIdx.y;          // 0..3
    const int t  = w * 64 + h;           // 0..255
    const int b  = blockIdx.y;
    const int i0 = blockIdx.x * ITILE;

    const float* zbase = zi + ((size_t)b * NN + i0) * HH;
    const float zv0 = zbase[(w * 2 + 0) * HH + h];
    const float zv1 = zbase[(w * 2 + 1) * HH + h];
    float a0 = 0.f, a1 = 0.f;

    const float* zjb_b = zjb + (size_t)b * NN * HH;

    for (int j0 = 0; j0 < NN; j0 += JT) {
        // cooperative stage: JT*HH = 8192 floats = 2048 float4, 8 per thread
        const float4* src = (const float4*)(zjb_b + (size_t)j0 * HH);
        float4* dst = (float4*)sj;
#pragma unroll
        for (int k = 0; k < 8; ++k) dst[t + k * 256] = src[t + k * 256];
        __syncthreads();
#pragma unroll 8
        for (int j = 0; j < JT; ++j) {
            const float zjv = sj[j * HH + h];   // 2-way bank alias: free
            a0 += fmaxf(zv0 + zjv, 0.f);
            a1 += fmaxf(zv1 + zjv, 0.f);
        }
        __syncthreads();
    }

    racc[w * 2 + 0][h] = a0;
    racc[w * 2 + 1][h] = a1;
    __syncthreads();

    // Epilogue: 8 rows x 30 outputs = 240 dots of length 64
    const int i = t >> 5;        // 0..7
    const int o = t & 31;        // 0..31
    if (o < OO) {
        float s = ba[o];
#pragma unroll
        for (int hh = 0; hh < HH; ++hh)
            s += racc[i][hh] * Wa[hh * OO + o];   // racc broadcast, Wa cached
        out[((size_t)b * NN + i0 + i) * OO + o] = fmaxf(s, 0.f);
    }
}

extern "C" void kernel_launch(void* const* d_in, const int* in_sizes, int n_in,
                              void* d_out, int out_size, void* d_ws, size_t ws_size,
                              hipStream_t stream) {
    const float* z_t = (const float*)d_in[0];   // [B,N,D]
    const float* W_r = (const float*)d_in[1];   // [2D,H]
    const float* b_r = (const float*)d_in[2];   // [H]
    const float* W_a = (const float*)d_in[3];   // [H,O]
    const float* b_a = (const float*)d_in[4];   // [O]
    float* out = (float*)d_out;                 // [B,N,O]

    float* zi  = (float*)d_ws;                  // B*N*H floats
    float* zjb = zi + (size_t)BB * NN * HH;     // B*N*H floats (1 MB total)

    proj_kernel<<<dim3((BB * NN) / 4), dim3(64, 4), 0, stream>>>(
        z_t, W_r, b_r, zi, zjb);
    pairsum_kernel<<<dim3(NN / ITILE, BB), dim3(64, 4), 0, stream>>>(
        zi, zjb, W_a, b_a, out);
}

// Round 4
// 79.639 us; speedup vs baseline: 1.1995x; 1.0731x over previous
//
#include <hip/hip_runtime.h>
#include <hip/hip_bf16.h>

// Problem: B=2, N=1024, D=30, H=64, O=30  (all fp32)
//   zi = z @ W_r[:D], zj = z @ W_r[D:]
//   r_sum[b,i,h] = sum_j relu(zi[b,i,h] + zj[b,j,h] + b_r[h])
//   out[b,i,o]   = relu(sum_h r_sum[b,i,h]*W_a[h,o] + b_a[o])
//
// R3 state: dur_us 85.5, dominated by harness d_ws poison fills (~40.3 us
// each, 268 MB @ 83% HBM peak). Open question: 1 or 2 fills per timed iter.
// R4 experiment: pairsum was 1 wave/SIMD (256 blocks) -> ds_read latency
// unhidden. This version: 512-thread blocks, 8 waves, j-range split in half
// across wave groups -> 2 waves/SIMD for latency hiding, same total issue.
// Halves combine in LDS; epilogue unchanged. If dur_us doesn't move,
// the ~81 us external fill floor is confirmed.

#define BB 2
#define NN 1024
#define DD 30
#define HH 64
#define OO 30
#define JT 128      // j-tile rows staged in LDS per half (32 KB)
#define ITILE 8     // i rows per block (each wave quad: 2 rows/wave)

typedef float v2f __attribute__((ext_vector_type(2)));

// Kernel A: compute zi[b,n,h] and zjb[b,n,h] = zj + b_r  (b_r folded here)
__global__ __launch_bounds__(256) void proj_kernel(
    const float* __restrict__ z,    // [B*N, D]
    const float* __restrict__ Wr,   // [2D, H]
    const float* __restrict__ br,   // [H]
    float* __restrict__ zi_out,     // [B*N, H]
    float* __restrict__ zjb_out)    // [B*N, H]
{
    const int h = threadIdx.x;                      // 0..63
    const int r = blockIdx.x * 4 + threadIdx.y;     // row in [0, B*N)
    const float* zrow = z + (size_t)r * DD;
    float wi = 0.f, wj = 0.f;
#pragma unroll
    for (int d = 0; d < DD; ++d) {
        const float zv = zrow[d];                   // wave-uniform (scalar)
        wi += zv * Wr[d * HH + h];                  // coalesced across lanes
        wj += zv * Wr[(DD + d) * HH + h];
    }
    zi_out [(size_t)r * HH + h] = wi;
    zjb_out[(size_t)r * HH + h] = wj + br[h];
}

// Kernel B: pairwise relu-sum over j, fused with the H->O epilogue GEMM.
// Grid: (N/ITILE, B). Block: (64, 8) = 512 threads, 8 waves.
// Waves 0-3 (half 0) process j in [0,512); waves 4-7 (half 1) j in [512,1024).
// Within a half, wave q owns i-rows i0+2q, i0+2q+1. 2 waves/SIMD hide LDS
// latency. Halves' partial sums combine in LDS before the epilogue.
__global__ __launch_bounds__(512) void pairsum_kernel(
    const float* __restrict__ zi,    // [B*N, H]
    const float* __restrict__ zjb,   // [B*N, H]
    const float* __restrict__ Wa,    // [H, O]
    const float* __restrict__ ba,    // [O]
    float* __restrict__ out)         // [B*N, O]
{
    __shared__ float sj[2][JT * HH];        // 2 x 32 KB j-tiles
    __shared__ float racc[2][ITILE][HH];    // 2 x 2 KB partial r_sum rows

    const int h  = threadIdx.x;          // 0..63
    const int w  = threadIdx.y;          // 0..7
    const int hf = w >> 2;               // j-half: 0 or 1
    const int wq = w & 3;                // wave-quad index within half
    const int t4 = wq * 64 + h;          // 0..255 within half
    const int b  = blockIdx.y;
    const int i0 = blockIdx.x * ITILE;

    const float* zbase = zi + ((size_t)b * NN + i0) * HH;
    v2f zv;
    zv.x = zbase[(wq * 2 + 0) * HH + h];
    zv.y = zbase[(wq * 2 + 1) * HH + h];
    v2f acc = {0.f, 0.f};

    // this half's 512-row slab of zjb
    const float* slab = zjb + ((size_t)b * NN + hf * (NN / 2)) * HH;

    for (int tile = 0; tile < (NN / 2) / JT; ++tile) {
        // cooperative stage: JT*HH = 8192 floats = 2048 float4, 8/thread
        const float4* src = (const float4*)(slab + (size_t)tile * JT * HH);
        float4* dst = (float4*)sj[hf];
#pragma unroll
        for (int k = 0; k < 8; ++k) dst[t4 + k * 256] = src[t4 + k * 256];
        __syncthreads();
        const float* sjt = sj[hf];
#pragma unroll 8
        for (int j = 0; j < JT; ++j) {
            const float zjv = sjt[j * HH + h];   // 2-way bank alias: free
            v2f tt = zv + zjv;                   // packable: v_pk_add_f32
            tt.x = fmaxf(tt.x, 0.f);             // v_max_f32 on pair regs
            tt.y = fmaxf(tt.y, 0.f);
            acc += tt;                           // packable: v_pk_add_f32
        }
        __syncthreads();
    }

    racc[hf][wq * 2 + 0][h] = acc.x;
    racc[hf][wq * 2 + 1][h] = acc.y;
    __syncthreads();

    // Epilogue: 8 rows x 30 outputs = 240 dots of length 64 (threads t<256)
    const int t = w * 64 + h;
    const int i = t >> 5;        // 0..7 for t<256
    const int o = t & 31;        // 0..31
    if (t < 256 && o < OO) {
        float s = ba[o];
#pragma unroll
        for (int hh = 0; hh < HH; ++hh)
            s += (racc[0][i][hh] + racc[1][i][hh]) * Wa[hh * OO + o];
        out[((size_t)b * NN + i0 + i) * OO + o] = fmaxf(s, 0.f);
    }
}

extern "C" void kernel_launch(void* const* d_in, const int* in_sizes, int n_in,
                              void* d_out, int out_size, void* d_ws, size_t ws_size,
                              hipStream_t stream) {
    const float* z_t = (const float*)d_in[0];   // [B,N,D]
    const float* W_r = (const float*)d_in[1];   // [2D,H]
    const float* b_r = (const float*)d_in[2];   // [H]
    const float* W_a = (const float*)d_in[3];   // [H,O]
    const float* b_a = (const float*)d_in[4];   // [O]
    float* out = (float*)d_out;                 // [B,N,O]

    float* zi  = (float*)d_ws;                  // B*N*H floats
    float* zjb = zi + (size_t)BB * NN * HH;     // B*N*H floats (1 MB total)

    proj_kernel<<<dim3((BB * NN) / 4), dim3(64, 4), 0, stream>>>(
        z_t, W_r, b_r, zi, zjb);
    pairsum_kernel<<<dim3(NN / ITILE, BB), dim3(64, 8), 0, stream>>>(
        zi, zjb, W_a, b_a, out);
}